// Round 1
// baseline (237.007 us; speedup 1.0000x reference)
//
#include <hip/hip_runtime.h>
#include <hip/hip_bf16.h>

#define NB 2
#define NT 2048
#define NC 1024
#define NHD 16
#define HDD 64

typedef __attribute__((ext_vector_type(8))) short short8;
typedef __attribute__((ext_vector_type(4))) float f32x4;

__device__ __forceinline__ ushort f2bf(float f) {
    union { float f; unsigned u; } v; v.f = f;
    unsigned u = v.u;
    unsigned r = (u + 0x7FFFu + ((u >> 16) & 1u)) >> 16;
    return (ushort)r;
}

// ---------------- elementwise f32 -> bf16 ----------------
__global__ __launch_bounds__(256)
void cvtx(const float* __restrict__ src, ushort* __restrict__ dst, int n)
{
    int i = (blockIdx.x * 256 + threadIdx.x) * 8;
    if (i >= n) return;
    float4 a = *(const float4*)(src + i);
    float4 b = *(const float4*)(src + i + 4);
    short8 o;
    o[0] = (short)f2bf(a.x); o[1] = (short)f2bf(a.y);
    o[2] = (short)f2bf(a.z); o[3] = (short)f2bf(a.w);
    o[4] = (short)f2bf(b.x); o[5] = (short)f2bf(b.y);
    o[6] = (short)f2bf(b.z); o[7] = (short)f2bf(b.w);
    *(short8*)(dst + i) = o;
}

// ---------------- transpose + convert: W[K][N] f32 -> Wt[N][K] bf16 ----------------
__global__ __launch_bounds__(256)
void tcvt(const float* __restrict__ src, ushort* __restrict__ dst, int Kd, int Nd)
{
    __shared__ ushort tile[64][68];
    const int tid = threadIdx.x;
    const int kb = blockIdx.x * 64, nb = blockIdx.y * 64;
    const int r = tid >> 2, c = (tid & 3) * 16;
    const float* sp = src + (size_t)(kb + r) * Nd + nb + c;
#pragma unroll
    for (int i = 0; i < 16; i += 4) {
        float4 v = *(const float4*)(sp + i);
        tile[r][c + i + 0] = f2bf(v.x);
        tile[r][c + i + 1] = f2bf(v.y);
        tile[r][c + i + 2] = f2bf(v.z);
        tile[r][c + i + 3] = f2bf(v.w);
    }
    __syncthreads();
    ushort* dp = dst + (size_t)(nb + r) * Kd + kb + c;
#pragma unroll
    for (int i = 0; i < 16; i += 8) {
        short8 o;
#pragma unroll
        for (int j = 0; j < 8; j++) o[j] = (short)tile[c + i + j][r];
        *(short8*)(dp + i) = o;
    }
}

// ---------------- 128x128 bf16 MFMA GEMM: C = A[M][K] * Bt[N][K]^T ----------------
// MODE 0: QKV projection epilogue (scatter to Q,K,V with bias, Q scaled 1/8)
// MODE 1: output projection epilogue (f32 + bias to Fo)
template<int MODE>
__global__ __launch_bounds__(256)
void gemm128(const ushort* __restrict__ A, const ushort* __restrict__ Bt,
             const float* __restrict__ bias0, const float* __restrict__ bias1,
             ushort* __restrict__ Qo, ushort* __restrict__ Ko, ushort* __restrict__ Vo,
             float* __restrict__ Fo, int Kdim)
{
    __shared__ ushort Al[128][40];
    __shared__ ushort Bl[128][40];
    const int tid = threadIdx.x;
    const int lane = tid & 63, w = tid >> 6;
    const int wr = (w >> 1) * 64, wc = (w & 1) * 64;
    const int lg = lane >> 4, lc = lane & 15;
    const int bm = blockIdx.x * 128, bn = blockIdx.y * 128;

    f32x4 acc[4][4] = {};

    const int r = tid >> 1, cs = (tid & 1) * 16;
    const ushort* ap = A + (size_t)(bm + r) * Kdim + cs;
    const ushort* bp = Bt + (size_t)(bn + r) * Kdim + cs;

    for (int k0 = 0; k0 < Kdim; k0 += 32) {
        __syncthreads();
        *(short8*)&Al[r][cs]     = *(const short8*)(ap + k0);
        *(short8*)&Al[r][cs + 8] = *(const short8*)(ap + k0 + 8);
        *(short8*)&Bl[r][cs]     = *(const short8*)(bp + k0);
        *(short8*)&Bl[r][cs + 8] = *(const short8*)(bp + k0 + 8);
        __syncthreads();
        short8 af[4], bfv[4];
#pragma unroll
        for (int mt = 0; mt < 4; mt++) af[mt] = *(const short8*)&Al[wr + mt*16 + lc][lg*8];
#pragma unroll
        for (int nt = 0; nt < 4; nt++) bfv[nt] = *(const short8*)&Bl[wc + nt*16 + lc][lg*8];
#pragma unroll
        for (int mt = 0; mt < 4; mt++)
#pragma unroll
            for (int nt = 0; nt < 4; nt++)
                acc[mt][nt] = __builtin_amdgcn_mfma_f32_16x16x32_bf16(af[mt], bfv[nt], acc[mt][nt], 0, 0, 0);
    }

#pragma unroll
    for (int mt = 0; mt < 4; mt++) {
#pragma unroll
        for (int nt = 0; nt < 4; nt++) {
#pragma unroll
            for (int rr = 0; rr < 4; rr++) {
                int m = bm + wr + mt*16 + lg*4 + rr;
                int n = bn + wc + nt*16 + lc;
                float v = acc[mt][nt][rr];
                if (MODE == 0) {
                    int b = m >> 11, t = m & 2047;
                    if (n < NC) {
                        float q = (v + bias0[n]) * 0.125f;
                        int hh = n >> 6, d = n & 63;
                        Qo[(((size_t)b*NHD + hh)*NT + t)*HDD + d] = f2bf(q);
                    } else {
                        int j = n - NC;
                        float val = v + bias1[j];
                        int s = j >> 10;
                        int jj = j & 1023;
                        int hh = jj >> 6, d = jj & 63;
                        ushort* dst = s ? Vo : Ko;
                        dst[(((size_t)b*NHD + hh)*NT + t)*HDD + d] = f2bf(val);
                    }
                } else {
                    Fo[(size_t)m * NC + n] = v + bias0[n];
                }
            }
        }
    }
}

// ---------------- flash attention with ALiBi + causal ----------------
__global__ __launch_bounds__(256)
void attn_fwd(const ushort* __restrict__ Q, const ushort* __restrict__ K,
              const ushort* __restrict__ V, ushort* __restrict__ Y)
{
    __shared__ ushort Kl[64][72];
    __shared__ ushort Vt[64][72];   // Vt[d][kv]
    __shared__ ushort Pl[4][16][72];

    const int tid = threadIdx.x;
    const int lane = tid & 63, w = tid >> 6;
    const int lg = lane >> 4, lc = lane & 15;
    const int qt = blockIdx.x & 31;
    const int bh = blockIdx.x >> 5;
    const int b = bh >> 4, h = bh & 15;

    const ushort* Qp = Q + (size_t)bh * NT * HDD;
    const ushort* Kp = K + (size_t)bh * NT * HDD;
    const ushort* Vp = V + (size_t)bh * NT * HDD;

    const int q0 = qt * 64 + w * 16;
    short8 qf0, qf1;
    {
        const ushort* qr = Qp + (size_t)(q0 + lc) * HDD + lg * 8;
        qf0 = *(const short8*)qr;
        qf1 = *(const short8*)(qr + 32);
    }
    float m_i[4], l_i[4];
    f32x4 acc[4] = {};
#pragma unroll
    for (int i = 0; i < 4; i++) { m_i[i] = -1e30f; l_i[i] = 0.f; }

    const float slope = (float)(h + 1) / (float)NHD;
    const int ntile = qt + 1;
    const int sr = tid >> 2, sd = (tid & 3) * 16;

    for (int t0 = 0; t0 < ntile; t0++) {
        const int kv0 = t0 * 64;
        __syncthreads();
        {
            const ushort* kp = Kp + (size_t)(kv0 + sr) * HDD + sd;
            *(short8*)&Kl[sr][sd]     = *(const short8*)kp;
            *(short8*)&Kl[sr][sd + 8] = *(const short8*)(kp + 8);
            const ushort* vp = Vp + (size_t)(kv0 + sr) * HDD + sd;
            short8 v0 = *(const short8*)vp;
            short8 v1 = *(const short8*)(vp + 8);
#pragma unroll
            for (int i = 0; i < 8; i++) Vt[sd + i][sr] = (ushort)v0[i];
#pragma unroll
            for (int i = 0; i < 8; i++) Vt[sd + 8 + i][sr] = (ushort)v1[i];
        }
        __syncthreads();

        f32x4 s[4];
#pragma unroll
        for (int kt = 0; kt < 4; kt++) {
            short8 kf0 = *(const short8*)&Kl[kt*16 + lc][lg*8];
            short8 kf1 = *(const short8*)&Kl[kt*16 + lc][32 + lg*8];
            f32x4 z = {0.f, 0.f, 0.f, 0.f};
            z = __builtin_amdgcn_mfma_f32_16x16x32_bf16(qf0, kf0, z, 0, 0, 0);
            s[kt] = __builtin_amdgcn_mfma_f32_16x16x32_bf16(qf1, kf1, z, 0, 0, 0);
        }

        float p[4][4];
#pragma unroll
        for (int rr = 0; rr < 4; rr++) {
            const int qi = q0 + lg*4 + rr;
            float sv[4]; float rmax = -1e30f;
#pragma unroll
            for (int kt = 0; kt < 4; kt++) {
                int kj = kv0 + kt*16 + lc;
                float x = s[kt][rr] + slope * (float)(kj - qi);
                x = (kj > qi) ? -1e30f : x;
                sv[kt] = x;
                rmax = fmaxf(rmax, x);
            }
#pragma unroll
            for (int mm = 1; mm < 16; mm <<= 1) rmax = fmaxf(rmax, __shfl_xor(rmax, mm));
            float mn = fmaxf(m_i[rr], rmax);
            float sc = __expf(m_i[rr] - mn);
            m_i[rr] = mn;
            float rs = 0.f;
#pragma unroll
            for (int kt = 0; kt < 4; kt++) { float pv = __expf(sv[kt] - mn); p[rr][kt] = pv; rs += pv; }
#pragma unroll
            for (int mm = 1; mm < 16; mm <<= 1) rs += __shfl_xor(rs, mm);
            l_i[rr] = l_i[rr] * sc + rs;
#pragma unroll
            for (int dt = 0; dt < 4; dt++) acc[dt][rr] *= sc;
        }
#pragma unroll
        for (int rr = 0; rr < 4; rr++)
#pragma unroll
            for (int kt = 0; kt < 4; kt++)
                Pl[w][lg*4 + rr][kt*16 + lc] = f2bf(p[rr][kt]);
        __syncthreads();
        short8 pa0 = *(const short8*)&Pl[w][lc][lg*8];
        short8 pa1 = *(const short8*)&Pl[w][lc][32 + lg*8];
#pragma unroll
        for (int dt = 0; dt < 4; dt++) {
            short8 vb0 = *(const short8*)&Vt[dt*16 + lc][lg*8];
            short8 vb1 = *(const short8*)&Vt[dt*16 + lc][32 + lg*8];
            acc[dt] = __builtin_amdgcn_mfma_f32_16x16x32_bf16(pa0, vb0, acc[dt], 0, 0, 0);
            acc[dt] = __builtin_amdgcn_mfma_f32_16x16x32_bf16(pa1, vb1, acc[dt], 0, 0, 0);
        }
    }

#pragma unroll
    for (int dt = 0; dt < 4; dt++) {
#pragma unroll
        for (int rr = 0; rr < 4; rr++) {
            int t = q0 + lg*4 + rr;
            int d = dt*16 + lc;
            float o = acc[dt][rr] / l_i[rr];
            Y[((size_t)b * NT + t) * NC + h * HDD + d] = f2bf(o);
        }
    }
}

extern "C" void kernel_launch(void* const* d_in, const int* in_sizes, int n_in,
                              void* d_out, int out_size, void* d_ws, size_t ws_size,
                              hipStream_t stream)
{
    const float* x    = (const float*)d_in[0];
    const float* q_w  = (const float*)d_in[1];
    const float* q_b  = (const float*)d_in[2];
    const float* kv_w = (const float*)d_in[3];
    const float* kv_b = (const float*)d_in[4];
    const float* o_w  = (const float*)d_in[5];
    const float* o_b  = (const float*)d_in[6];
    float* out = (float*)d_out;

    char* ws = (char*)d_ws;
    ushort* xb    = (ushort*)(ws);                 // [4096][1024] bf16     8 MB
    ushort* wqkvT = (ushort*)(ws + 8388608);       // [3072][1024] bf16     6 MB
    ushort* woT   = (ushort*)(ws + 14680064);      // [1024][1024] bf16     2 MB
    ushort* Qs    = (ushort*)(ws + 16777216);      // [B][NH][T][HD] bf16   8 MB
    ushort* Ks    = (ushort*)(ws + 25165824);
    ushort* Vs    = (ushort*)(ws + 33554432);
    ushort* Ys    = (ushort*)(ws + 41943040);      // [B][T][C] bf16        8 MB

    cvtx<<<2048, 256, 0, stream>>>(x, xb, NB*NT*NC);
    tcvt<<<dim3(16,16), 256, 0, stream>>>(q_w, wqkvT, 1024, 1024);
    tcvt<<<dim3(16,32), 256, 0, stream>>>(kv_w, wqkvT + 1024*1024, 1024, 2048);
    tcvt<<<dim3(16,16), 256, 0, stream>>>(o_w, woT, 1024, 1024);
    gemm128<0><<<dim3(32,24), 256, 0, stream>>>(xb, wqkvT, q_b, kv_b, Qs, Ks, Vs, nullptr, 1024);
    attn_fwd<<<1024, 256, 0, stream>>>(Qs, Ks, Vs, Ys);
    gemm128<1><<<dim3(32,8), 256, 0, stream>>>(Ys, woT, o_b, nullptr, nullptr, nullptr, nullptr, out, 1024);
}

// Round 2
// 175.477 us; speedup vs baseline: 1.3506x; 1.3506x over previous
//
#include <hip/hip_runtime.h>
#include <hip/hip_bf16.h>

#define NB 2
#define NT 2048
#define NC 1024
#define NHD 16
#define HDD 64
#define LOG2E 1.4426950408889634f

typedef __attribute__((ext_vector_type(8))) short short8;
typedef __attribute__((ext_vector_type(4))) float f32x4;

__device__ __forceinline__ ushort f2bf(float f) {
    union { float f; unsigned u; } v; v.f = f;
    unsigned u = v.u;
    unsigned r = (u + 0x7FFFu + ((u >> 16) & 1u)) >> 16;
    return (ushort)r;
}

// ---------------- elementwise f32 -> bf16 ----------------
__global__ __launch_bounds__(256)
void cvtx(const float* __restrict__ src, ushort* __restrict__ dst, int n)
{
    int i = (blockIdx.x * 256 + threadIdx.x) * 8;
    if (i >= n) return;
    float4 a = *(const float4*)(src + i);
    float4 b = *(const float4*)(src + i + 4);
    short8 o;
    o[0] = (short)f2bf(a.x); o[1] = (short)f2bf(a.y);
    o[2] = (short)f2bf(a.z); o[3] = (short)f2bf(a.w);
    o[4] = (short)f2bf(b.x); o[5] = (short)f2bf(b.y);
    o[6] = (short)f2bf(b.z); o[7] = (short)f2bf(b.w);
    *(short8*)(dst + i) = o;
}

// ---------------- transpose + convert: W[K][N] f32 -> Wt[N][K] bf16 ----------------
__global__ __launch_bounds__(256)
void tcvt(const float* __restrict__ src, ushort* __restrict__ dst, int Kd, int Nd)
{
    __shared__ ushort tile[64][68];
    const int tid = threadIdx.x;
    const int kb = blockIdx.x * 64, nb = blockIdx.y * 64;
    const int r = tid >> 2, c = (tid & 3) * 16;
    const float* sp = src + (size_t)(kb + r) * Nd + nb + c;
#pragma unroll
    for (int i = 0; i < 16; i += 4) {
        float4 v = *(const float4*)(sp + i);
        tile[r][c + i + 0] = f2bf(v.x);
        tile[r][c + i + 1] = f2bf(v.y);
        tile[r][c + i + 2] = f2bf(v.z);
        tile[r][c + i + 3] = f2bf(v.w);
    }
    __syncthreads();
    ushort* dp = dst + (size_t)(nb + r) * Kd + kb + c;
#pragma unroll
    for (int i = 0; i < 16; i += 8) {
        short8 o;
#pragma unroll
        for (int j = 0; j < 8; j++) o[j] = (short)tile[c + i + j][r];
        *(short8*)(dp + i) = o;
    }
}

// ---------------- bf16 transpose: V[bh][t][d] -> Vt[bh][d][t] ----------------
__global__ __launch_bounds__(256)
void vtr(const ushort* __restrict__ src, ushort* __restrict__ dst)
{
    __shared__ ushort tile[64][66];
    const int tid = threadIdx.x;
    const int bh = blockIdx.y;
    const int t0 = blockIdx.x * 64;
    const int r = tid >> 2, c = (tid & 3) * 16;
    const ushort* sp = src + ((size_t)bh * NT + t0 + r) * HDD + c;
    *(short8*)&tile[r][c]     = *(const short8*)sp;
    *(short8*)&tile[r][c + 8] = *(const short8*)(sp + 8);
    __syncthreads();
    ushort* dp = dst + ((size_t)bh * HDD + r) * NT + t0 + c;
    short8 o0, o1;
#pragma unroll
    for (int j = 0; j < 8; j++) { o0[j] = (short)tile[c + j][r]; o1[j] = (short)tile[c + 8 + j][r]; }
    *(short8*)dp = o0;
    *(short8*)(dp + 8) = o1;
}

// ---------------- 128x128 bf16 MFMA GEMM: C = A[M][K] * Bt[N][K]^T ----------------
template<int MODE>
__global__ __launch_bounds__(256)
void gemm128(const ushort* __restrict__ A, const ushort* __restrict__ Bt,
             const float* __restrict__ bias0, const float* __restrict__ bias1,
             ushort* __restrict__ Qo, ushort* __restrict__ Ko, ushort* __restrict__ Vo,
             float* __restrict__ Fo, int Kdim)
{
    __shared__ ushort Al[128][40];
    __shared__ ushort Bl[128][40];
    const int tid = threadIdx.x;
    const int lane = tid & 63, w = tid >> 6;
    const int wr = (w >> 1) * 64, wc = (w & 1) * 64;
    const int lg = lane >> 4, lc = lane & 15;
    const int bm = blockIdx.x * 128, bn = blockIdx.y * 128;

    f32x4 acc[4][4] = {};

    const int r = tid >> 1, cs = (tid & 1) * 16;
    const ushort* ap = A + (size_t)(bm + r) * Kdim + cs;
    const ushort* bp = Bt + (size_t)(bn + r) * Kdim + cs;

    for (int k0 = 0; k0 < Kdim; k0 += 32) {
        __syncthreads();
        *(short8*)&Al[r][cs]     = *(const short8*)(ap + k0);
        *(short8*)&Al[r][cs + 8] = *(const short8*)(ap + k0 + 8);
        *(short8*)&Bl[r][cs]     = *(const short8*)(bp + k0);
        *(short8*)&Bl[r][cs + 8] = *(const short8*)(bp + k0 + 8);
        __syncthreads();
        short8 af[4], bfv[4];
#pragma unroll
        for (int mt = 0; mt < 4; mt++) af[mt] = *(const short8*)&Al[wr + mt*16 + lc][lg*8];
#pragma unroll
        for (int nt = 0; nt < 4; nt++) bfv[nt] = *(const short8*)&Bl[wc + nt*16 + lc][lg*8];
#pragma unroll
        for (int mt = 0; mt < 4; mt++)
#pragma unroll
            for (int nt = 0; nt < 4; nt++)
                acc[mt][nt] = __builtin_amdgcn_mfma_f32_16x16x32_bf16(af[mt], bfv[nt], acc[mt][nt], 0, 0, 0);
    }

#pragma unroll
    for (int mt = 0; mt < 4; mt++) {
#pragma unroll
        for (int nt = 0; nt < 4; nt++) {
#pragma unroll
            for (int rr = 0; rr < 4; rr++) {
                int m = bm + wr + mt*16 + lg*4 + rr;
                int n = bn + wc + nt*16 + lc;
                float v = acc[mt][nt][rr];
                if (MODE == 0) {
                    int b = m >> 11, t = m & 2047;
                    if (n < NC) {
                        float q = (v + bias0[n]) * (0.125f * LOG2E);
                        int hh = n >> 6, d = n & 63;
                        Qo[(((size_t)b*NHD + hh)*NT + t)*HDD + d] = f2bf(q);
                    } else {
                        int j = n - NC;
                        float val = v + bias1[j];
                        int s = j >> 10;
                        int jj = j & 1023;
                        int hh = jj >> 6, d = jj & 63;
                        ushort* dst = s ? Vo : Ko;
                        dst[(((size_t)b*NHD + hh)*NT + t)*HDD + d] = f2bf(val);
                    }
                } else {
                    Fo[(size_t)m * NC + n] = v + bias0[n];
                }
            }
        }
    }
}

// ---------------- flash attention with ALiBi + causal (log2 domain) ----------------
// Grid: 512 blocks; block = pair of q-chunks (p, 31-p) => exactly 33 KV tiles each.
// Block id swizzled so all 16 blocks of one (b,h) land on the same XCD.
__global__ __launch_bounds__(256)
void attn_fwd(const ushort* __restrict__ Q, const ushort* __restrict__ K,
              const ushort* __restrict__ Vt, ushort* __restrict__ Y)
{
    __shared__ ushort Kl[64][72];
    __shared__ ushort Vl[64][72];   // Vl[d][kv]
    __shared__ ushort Pl[4][16][72];

    const int tid = threadIdx.x;
    const int lane = tid & 63, w = tid >> 6;
    const int lg = lane >> 4, lc = lane & 15;
    const int i = blockIdx.x;
    const int p = (i >> 3) & 15;
    const int bh = ((i >> 7) << 3) | (i & 7);
    const int b = bh >> 4, h = bh & 15;

    const ushort* Qp = Q + (size_t)bh * NT * HDD;
    const ushort* Kp = K + (size_t)bh * NT * HDD;
    const ushort* Vp = Vt + (size_t)bh * HDD * NT;

    const float slope2 = (float)(h + 1) * (LOG2E / (float)NHD);
    const int sr = tid >> 2, sd = (tid & 3) * 16;
    const float alk0 = slope2 * (float)lc;
    const float s16 = slope2 * 16.0f;

    short8 ones;
#pragma unroll
    for (int j = 0; j < 8; j++) ones[j] = (short)0x3F80;

    for (int ci = 0; ci < 2; ci++) {
        const int qt = ci ? (31 - p) : p;
        const int q0 = qt * 64 + w * 16;

        short8 qf0, qf1;
        {
            const ushort* qr = Qp + (size_t)(q0 + lc) * HDD + lg * 8;
            qf0 = *(const short8*)qr;
            qf1 = *(const short8*)(qr + 32);
        }
        float m_i[4], l_i[4], sc[4];
        f32x4 acc[4] = {};
#pragma unroll
        for (int r4 = 0; r4 < 4; r4++) { m_i[r4] = -1e30f; l_i[r4] = 0.f; }

        const int ntile = qt + 1;
        for (int t0 = 0; t0 < ntile; t0++) {
            const int kv0 = t0 * 64;
            __syncthreads();
            {
                const ushort* kp = Kp + (size_t)(kv0 + sr) * HDD + sd;
                *(short8*)&Kl[sr][sd]     = *(const short8*)kp;
                *(short8*)&Kl[sr][sd + 8] = *(const short8*)(kp + 8);
                const ushort* vp = Vp + (size_t)sr * NT + kv0 + sd;
                *(short8*)&Vl[sr][sd]     = *(const short8*)vp;
                *(short8*)&Vl[sr][sd + 8] = *(const short8*)(vp + 8);
            }
            __syncthreads();

            f32x4 s[4];
#pragma unroll
            for (int kt = 0; kt < 4; kt++) {
                short8 kf0 = *(const short8*)&Kl[kt*16 + lc][lg*8];
                short8 kf1 = *(const short8*)&Kl[kt*16 + lc][32 + lg*8];
                f32x4 z = {0.f, 0.f, 0.f, 0.f};
                z = __builtin_amdgcn_mfma_f32_16x16x32_bf16(qf0, kf0, z, 0, 0, 0);
                s[kt] = __builtin_amdgcn_mfma_f32_16x16x32_bf16(qf1, kf1, z, 0, 0, 0);
            }

            // ALiBi bias (row-constant term dropped; cancels in softmax)
            float bk[4];
            bk[0] = slope2 * (float)kv0 + alk0;
            bk[1] = bk[0] + s16; bk[2] = bk[1] + s16; bk[3] = bk[2] + s16;

            const bool diag = (t0 == qt);
#pragma unroll
            for (int rr = 0; rr < 4; rr++) {
                float x[4];
#pragma unroll
                for (int kt = 0; kt < 4; kt++) x[kt] = s[kt][rr] + bk[kt];
                if (diag) {
                    const int qi = q0 + lg*4 + rr;
#pragma unroll
                    for (int kt = 0; kt < 4; kt++) {
                        int kj = kv0 + kt*16 + lc;
                        x[kt] = (kj > qi) ? -1e30f : x[kt];
                    }
                }
                float rmax = fmaxf(fmaxf(x[0], x[1]), fmaxf(x[2], x[3]));
#pragma unroll
                for (int mm = 1; mm < 16; mm <<= 1) rmax = fmaxf(rmax, __shfl_xor(rmax, mm));
                float mn = fmaxf(m_i[rr], rmax);
                sc[rr] = exp2f(m_i[rr] - mn);
                m_i[rr] = mn;
#pragma unroll
                for (int kt = 0; kt < 4; kt++) {
                    float pv = exp2f(x[kt] - mn);
                    unsigned pb; __builtin_memcpy(&pb, &pv, 4);
                    Pl[w][lg*4 + rr][kt*16 + lc] = (ushort)(pb >> 16);
                }
#pragma unroll
                for (int dt = 0; dt < 4; dt++) acc[dt][rr] *= sc[rr];
            }

            short8 pa0 = *(const short8*)&Pl[w][lc][lg*8];
            short8 pa1 = *(const short8*)&Pl[w][lc][32 + lg*8];

            f32x4 rsv = {0.f, 0.f, 0.f, 0.f};
            rsv = __builtin_amdgcn_mfma_f32_16x16x32_bf16(pa0, ones, rsv, 0, 0, 0);
            rsv = __builtin_amdgcn_mfma_f32_16x16x32_bf16(pa1, ones, rsv, 0, 0, 0);

#pragma unroll
            for (int dt = 0; dt < 4; dt++) {
                short8 vb0 = *(const short8*)&Vl[dt*16 + lc][lg*8];
                short8 vb1 = *(const short8*)&Vl[dt*16 + lc][32 + lg*8];
                acc[dt] = __builtin_amdgcn_mfma_f32_16x16x32_bf16(pa0, vb0, acc[dt], 0, 0, 0);
                acc[dt] = __builtin_amdgcn_mfma_f32_16x16x32_bf16(pa1, vb1, acc[dt], 0, 0, 0);
            }
#pragma unroll
            for (int rr = 0; rr < 4; rr++) l_i[rr] = l_i[rr] * sc[rr] + rsv[rr];
        }

        float inv[4];
#pragma unroll
        for (int rr = 0; rr < 4; rr++) inv[rr] = __builtin_amdgcn_rcpf(l_i[rr]);
#pragma unroll
        for (int dt = 0; dt < 4; dt++) {
#pragma unroll
            for (int rr = 0; rr < 4; rr++) {
                int t = q0 + lg*4 + rr;
                int d = dt*16 + lc;
                Y[((size_t)b * NT + t) * NC + h * HDD + d] = f2bf(acc[dt][rr] * inv[rr]);
            }
        }
    }
}

extern "C" void kernel_launch(void* const* d_in, const int* in_sizes, int n_in,
                              void* d_out, int out_size, void* d_ws, size_t ws_size,
                              hipStream_t stream)
{
    const float* x    = (const float*)d_in[0];
    const float* q_w  = (const float*)d_in[1];
    const float* q_b  = (const float*)d_in[2];
    const float* kv_w = (const float*)d_in[3];
    const float* kv_b = (const float*)d_in[4];
    const float* o_w  = (const float*)d_in[5];
    const float* o_b  = (const float*)d_in[6];
    float* out = (float*)d_out;

    char* ws = (char*)d_ws;
    ushort* xb    = (ushort*)(ws);                 // [4096][1024] bf16     8 MB  (reused as VsT after gemm<0>)
    ushort* wqkvT = (ushort*)(ws + 8388608);       // [3072][1024] bf16     6 MB
    ushort* woT   = (ushort*)(ws + 14680064);      // [1024][1024] bf16     2 MB
    ushort* Qs    = (ushort*)(ws + 16777216);      // [B][NH][T][HD] bf16   8 MB
    ushort* Ks    = (ushort*)(ws + 25165824);
    ushort* Vs    = (ushort*)(ws + 33554432);
    ushort* Ys    = (ushort*)(ws + 41943040);      // [B][T][C] bf16        8 MB
    ushort* VsT   = xb;                            // [B][NH][HD][T] bf16   8 MB

    cvtx<<<2048, 256, 0, stream>>>(x, xb, NB*NT*NC);
    tcvt<<<dim3(16,16), 256, 0, stream>>>(q_w, wqkvT, 1024, 1024);
    tcvt<<<dim3(16,32), 256, 0, stream>>>(kv_w, wqkvT + 1024*1024, 1024, 2048);
    tcvt<<<dim3(16,16), 256, 0, stream>>>(o_w, woT, 1024, 1024);
    gemm128<0><<<dim3(32,24), 256, 0, stream>>>(xb, wqkvT, q_b, kv_b, Qs, Ks, Vs, nullptr, 1024);
    vtr<<<dim3(32,32), 256, 0, stream>>>(Vs, VsT);
    attn_fwd<<<512, 256, 0, stream>>>(Qs, Ks, VsT, Ys);
    gemm128<1><<<dim3(32,8), 256, 0, stream>>>(Ys, woT, o_b, nullptr, nullptr, nullptr, nullptr, out, 1024);
}

// Round 3
// 162.404 us; speedup vs baseline: 1.4594x; 1.0805x over previous
//
#include <hip/hip_runtime.h>
#include <hip/hip_bf16.h>

#define NB 2
#define NT 2048
#define NC 1024
#define NHD 16
#define HDD 64
#define LOG2E 1.4426950408889634f

typedef __attribute__((ext_vector_type(8))) short short8;
typedef __attribute__((ext_vector_type(4))) float f32x4;

__device__ __forceinline__ ushort f2bf(float f) {
    union { float f; unsigned u; } v; v.f = f;
    unsigned u = v.u;
    unsigned r = (u + 0x7FFFu + ((u >> 16) & 1u)) >> 16;
    return (ushort)r;
}

// ---------------- elementwise f32 -> bf16 ----------------
__global__ __launch_bounds__(256)
void cvtx(const float* __restrict__ src, ushort* __restrict__ dst, int n)
{
    int i = (blockIdx.x * 256 + threadIdx.x) * 8;
    if (i >= n) return;
    float4 a = *(const float4*)(src + i);
    float4 b = *(const float4*)(src + i + 4);
    short8 o;
    o[0] = (short)f2bf(a.x); o[1] = (short)f2bf(a.y);
    o[2] = (short)f2bf(a.z); o[3] = (short)f2bf(a.w);
    o[4] = (short)f2bf(b.x); o[5] = (short)f2bf(b.y);
    o[6] = (short)f2bf(b.z); o[7] = (short)f2bf(b.w);
    *(short8*)(dst + i) = o;
}

// ---------------- transpose + convert: W[K][N] f32 -> Wt[N][K] bf16 ----------------
__global__ __launch_bounds__(256)
void tcvt(const float* __restrict__ src, ushort* __restrict__ dst, int Kd, int Nd)
{
    __shared__ ushort tile[64][68];
    const int tid = threadIdx.x;
    const int kb = blockIdx.x * 64, nb = blockIdx.y * 64;
    const int r = tid >> 2, c = (tid & 3) * 16;
    const float* sp = src + (size_t)(kb + r) * Nd + nb + c;
#pragma unroll
    for (int i = 0; i < 16; i += 4) {
        float4 v = *(const float4*)(sp + i);
        tile[r][c + i + 0] = f2bf(v.x);
        tile[r][c + i + 1] = f2bf(v.y);
        tile[r][c + i + 2] = f2bf(v.z);
        tile[r][c + i + 3] = f2bf(v.w);
    }
    __syncthreads();
    ushort* dp = dst + (size_t)(nb + r) * Kd + kb + c;
#pragma unroll
    for (int i = 0; i < 16; i += 8) {
        short8 o;
#pragma unroll
        for (int j = 0; j < 8; j++) o[j] = (short)tile[c + i + j][r];
        *(short8*)(dp + i) = o;
    }
}

// ---------------- bf16 transpose: V[bh][t][d] -> Vt[bh][d][t] ----------------
__global__ __launch_bounds__(256)
void vtr(const ushort* __restrict__ src, ushort* __restrict__ dst)
{
    __shared__ ushort tile[64][66];
    const int tid = threadIdx.x;
    const int bh = blockIdx.y;
    const int t0 = blockIdx.x * 64;
    const int r = tid >> 2, c = (tid & 3) * 16;
    const ushort* sp = src + ((size_t)bh * NT + t0 + r) * HDD + c;
    *(short8*)&tile[r][c]     = *(const short8*)sp;
    *(short8*)&tile[r][c + 8] = *(const short8*)(sp + 8);
    __syncthreads();
    ushort* dp = dst + ((size_t)bh * HDD + r) * NT + t0 + c;
    short8 o0, o1;
#pragma unroll
    for (int j = 0; j < 8; j++) { o0[j] = (short)tile[c + j][r]; o1[j] = (short)tile[c + 8 + j][r]; }
    *(short8*)dp = o0;
    *(short8*)(dp + 8) = o1;
}

// ---------------- 128x128 bf16 MFMA GEMM: C = A[M][K] * Bt[N][K]^T ----------------
template<int MODE>
__global__ __launch_bounds__(256)
void gemm128(const ushort* __restrict__ A, const ushort* __restrict__ Bt,
             const float* __restrict__ bias0, const float* __restrict__ bias1,
             ushort* __restrict__ Qo, ushort* __restrict__ Ko, ushort* __restrict__ Vo,
             float* __restrict__ Fo, int Kdim)
{
    __shared__ ushort Al[128][40];
    __shared__ ushort Bl[128][40];
    const int tid = threadIdx.x;
    const int lane = tid & 63, w = tid >> 6;
    const int wr = (w >> 1) * 64, wc = (w & 1) * 64;
    const int lg = lane >> 4, lc = lane & 15;
    const int bm = blockIdx.x * 128, bn = blockIdx.y * 128;

    f32x4 acc[4][4] = {};

    const int r = tid >> 1, cs = (tid & 1) * 16;
    const ushort* ap = A + (size_t)(bm + r) * Kdim + cs;
    const ushort* bp = Bt + (size_t)(bn + r) * Kdim + cs;

    for (int k0 = 0; k0 < Kdim; k0 += 32) {
        __syncthreads();
        *(short8*)&Al[r][cs]     = *(const short8*)(ap + k0);
        *(short8*)&Al[r][cs + 8] = *(const short8*)(ap + k0 + 8);
        *(short8*)&Bl[r][cs]     = *(const short8*)(bp + k0);
        *(short8*)&Bl[r][cs + 8] = *(const short8*)(bp + k0 + 8);
        __syncthreads();
        short8 af[4], bfv[4];
#pragma unroll
        for (int mt = 0; mt < 4; mt++) af[mt] = *(const short8*)&Al[wr + mt*16 + lc][lg*8];
#pragma unroll
        for (int nt = 0; nt < 4; nt++) bfv[nt] = *(const short8*)&Bl[wc + nt*16 + lc][lg*8];
#pragma unroll
        for (int mt = 0; mt < 4; mt++)
#pragma unroll
            for (int nt = 0; nt < 4; nt++)
                acc[mt][nt] = __builtin_amdgcn_mfma_f32_16x16x32_bf16(af[mt], bfv[nt], acc[mt][nt], 0, 0, 0);
    }

#pragma unroll
    for (int mt = 0; mt < 4; mt++) {
#pragma unroll
        for (int nt = 0; nt < 4; nt++) {
#pragma unroll
            for (int rr = 0; rr < 4; rr++) {
                int m = bm + wr + mt*16 + lg*4 + rr;
                int n = bn + wc + nt*16 + lc;
                float v = acc[mt][nt][rr];
                if (MODE == 0) {
                    int b = m >> 11, t = m & 2047;
                    if (n < NC) {
                        float q = (v + bias0[n]) * (0.125f * LOG2E);
                        int hh = n >> 6, d = n & 63;
                        Qo[(((size_t)b*NHD + hh)*NT + t)*HDD + d] = f2bf(q);
                    } else {
                        int j = n - NC;
                        float val = v + bias1[j];
                        int s = j >> 10;
                        int jj = j & 1023;
                        int hh = jj >> 6, d = jj & 63;
                        ushort* dst = s ? Vo : Ko;
                        dst[(((size_t)b*NHD + hh)*NT + t)*HDD + d] = f2bf(val);
                    }
                } else {
                    Fo[(size_t)m * NC + n] = v + bias0[n];
                }
            }
        }
    }
}

// ---------------- flash attention with ALiBi + causal (log2 domain) ----------------
// 1024 blocks: one 64-row q-chunk each, heaviest chunks dispatched first.
// 4096 waves total -> 16 waves/CU resident. Reg-prefetch of next K/V tile (T14),
// defer-max rescale skip (T13), MFMA-ones row-sum, diag-only causal mask.
__global__ __launch_bounds__(256)
void attn_fwd(const ushort* __restrict__ Q, const ushort* __restrict__ K,
              const ushort* __restrict__ Vt, ushort* __restrict__ Y)
{
    __shared__ ushort Kl[64][72];
    __shared__ ushort Vl[64][72];   // Vl[d][kv]
    __shared__ ushort Pl[4][16][72];

    const int tid = threadIdx.x;
    const int lane = tid & 63, w = tid >> 6;
    const int lg = lane >> 4, lc = lane & 15;
    const int qt = 31 - (blockIdx.x >> 5);      // heavy chunks first
    const int bh = blockIdx.x & 31;
    const int b = bh >> 4, h = bh & 15;

    const ushort* Qp = Q + (size_t)bh * NT * HDD;
    const ushort* Kp = K + (size_t)bh * NT * HDD;
    const ushort* Vp = Vt + (size_t)bh * HDD * NT;

    const float slope2 = (float)(h + 1) * (LOG2E / (float)NHD);
    const int sr = tid >> 2, sd = (tid & 3) * 16;
    const float alk0 = slope2 * (float)lc;
    const float s16 = slope2 * 16.0f;

    short8 ones;
#pragma unroll
    for (int j = 0; j < 8; j++) ones[j] = (short)0x3F80;

    const int q0 = qt * 64 + w * 16;
    short8 qf0, qf1;
    {
        const ushort* qr = Qp + (size_t)(q0 + lc) * HDD + lg * 8;
        qf0 = *(const short8*)qr;
        qf1 = *(const short8*)(qr + 32);
    }
    float m_i[4], l_i[4], sc[4];
    f32x4 acc[4] = {};
#pragma unroll
    for (int r4 = 0; r4 < 4; r4++) { m_i[r4] = -1e30f; l_i[r4] = 0.f; }

    const int ntile = qt + 1;

    // prefetch tile 0 into registers
    short8 pk0, pk1, pv0, pv1;
    {
        const ushort* kp = Kp + (size_t)sr * HDD + sd;
        pk0 = *(const short8*)kp;
        pk1 = *(const short8*)(kp + 8);
        const ushort* vp = Vp + (size_t)sr * NT + sd;
        pv0 = *(const short8*)vp;
        pv1 = *(const short8*)(vp + 8);
    }

    for (int t0 = 0; t0 < ntile; t0++) {
        const int kv0 = t0 * 64;
        __syncthreads();                      // prior tile's reads complete
        *(short8*)&Kl[sr][sd]     = pk0;
        *(short8*)&Kl[sr][sd + 8] = pk1;
        *(short8*)&Vl[sr][sd]     = pv0;
        *(short8*)&Vl[sr][sd + 8] = pv1;
        __syncthreads();                      // staging visible

        if (t0 + 1 < ntile) {                 // issue next-tile loads early (T14)
            const int kv1 = kv0 + 64;
            const ushort* kp = Kp + (size_t)(kv1 + sr) * HDD + sd;
            pk0 = *(const short8*)kp;
            pk1 = *(const short8*)(kp + 8);
            const ushort* vp = Vp + (size_t)sr * NT + kv1 + sd;
            pv0 = *(const short8*)vp;
            pv1 = *(const short8*)(vp + 8);
        }

        f32x4 s[4];
#pragma unroll
        for (int kt = 0; kt < 4; kt++) {
            short8 kf0 = *(const short8*)&Kl[kt*16 + lc][lg*8];
            short8 kf1 = *(const short8*)&Kl[kt*16 + lc][32 + lg*8];
            f32x4 z = {0.f, 0.f, 0.f, 0.f};
            z = __builtin_amdgcn_mfma_f32_16x16x32_bf16(qf0, kf0, z, 0, 0, 0);
            s[kt] = __builtin_amdgcn_mfma_f32_16x16x32_bf16(qf1, kf1, z, 0, 0, 0);
        }

        // ALiBi bias (row-constant term dropped; cancels in softmax)
        float bk[4];
        bk[0] = slope2 * (float)kv0 + alk0;
        bk[1] = bk[0] + s16; bk[2] = bk[1] + s16; bk[3] = bk[2] + s16;

        const bool diag = (t0 == qt);
#pragma unroll
        for (int rr = 0; rr < 4; rr++) {
            float x[4];
#pragma unroll
            for (int kt = 0; kt < 4; kt++) x[kt] = s[kt][rr] + bk[kt];
            if (diag) {
                const int qi = q0 + lg*4 + rr;
#pragma unroll
                for (int kt = 0; kt < 4; kt++) {
                    int kj = kv0 + kt*16 + lc;
                    x[kt] = (kj > qi) ? -1e30f : x[kt];
                }
            }
            float rmax = fmaxf(fmaxf(x[0], x[1]), fmaxf(x[2], x[3]));
#pragma unroll
            for (int mm = 1; mm < 16; mm <<= 1) rmax = fmaxf(rmax, __shfl_xor(rmax, mm));
            if (rmax - m_i[rr] > 8.0f) {      // defer-max (T13)
                float mn = fmaxf(m_i[rr], rmax);
                sc[rr] = exp2f(m_i[rr] - mn);
                m_i[rr] = mn;
            } else {
                sc[rr] = 1.0f;
            }
#pragma unroll
            for (int kt = 0; kt < 4; kt++) {
                float pv = exp2f(x[kt] - m_i[rr]);
                unsigned pb; __builtin_memcpy(&pb, &pv, 4);
                Pl[w][lg*4 + rr][kt*16 + lc] = (ushort)(pb >> 16);
            }
        }
        if (__any(sc[0] != 1.0f || sc[1] != 1.0f || sc[2] != 1.0f || sc[3] != 1.0f)) {
#pragma unroll
            for (int dt = 0; dt < 4; dt++)
#pragma unroll
                for (int rr = 0; rr < 4; rr++) acc[dt][rr] *= sc[rr];
        }

        short8 pa0 = *(const short8*)&Pl[w][lc][lg*8];
        short8 pa1 = *(const short8*)&Pl[w][lc][32 + lg*8];

        f32x4 rsv = {0.f, 0.f, 0.f, 0.f};
        rsv = __builtin_amdgcn_mfma_f32_16x16x32_bf16(pa0, ones, rsv, 0, 0, 0);
        rsv = __builtin_amdgcn_mfma_f32_16x16x32_bf16(pa1, ones, rsv, 0, 0, 0);

#pragma unroll
        for (int dt = 0; dt < 4; dt++) {
            short8 vb0 = *(const short8*)&Vl[dt*16 + lc][lg*8];
            short8 vb1 = *(const short8*)&Vl[dt*16 + lc][32 + lg*8];
            acc[dt] = __builtin_amdgcn_mfma_f32_16x16x32_bf16(pa0, vb0, acc[dt], 0, 0, 0);
            acc[dt] = __builtin_amdgcn_mfma_f32_16x16x32_bf16(pa1, vb1, acc[dt], 0, 0, 0);
        }
#pragma unroll
        for (int rr = 0; rr < 4; rr++) l_i[rr] = l_i[rr] * sc[rr] + rsv[rr];
    }

    float inv[4];
#pragma unroll
    for (int rr = 0; rr < 4; rr++) inv[rr] = __builtin_amdgcn_rcpf(l_i[rr]);
#pragma unroll
    for (int dt = 0; dt < 4; dt++) {
#pragma unroll
        for (int rr = 0; rr < 4; rr++) {
            int t = q0 + lg*4 + rr;
            int d = dt*16 + lc;
            Y[((size_t)b * NT + t) * NC + h * HDD + d] = f2bf(acc[dt][rr] * inv[rr]);
        }
    }
}

extern "C" void kernel_launch(void* const* d_in, const int* in_sizes, int n_in,
                              void* d_out, int out_size, void* d_ws, size_t ws_size,
                              hipStream_t stream)
{
    const float* x    = (const float*)d_in[0];
    const float* q_w  = (const float*)d_in[1];
    const float* q_b  = (const float*)d_in[2];
    const float* kv_w = (const float*)d_in[3];
    const float* kv_b = (const float*)d_in[4];
    const float* o_w  = (const float*)d_in[5];
    const float* o_b  = (const float*)d_in[6];
    float* out = (float*)d_out;

    char* ws = (char*)d_ws;
    ushort* xb    = (ushort*)(ws);                 // [4096][1024] bf16     8 MB  (reused as VsT after gemm<0>)
    ushort* wqkvT = (ushort*)(ws + 8388608);       // [3072][1024] bf16     6 MB
    ushort* woT   = (ushort*)(ws + 14680064);      // [1024][1024] bf16     2 MB
    ushort* Qs    = (ushort*)(ws + 16777216);      // [B][NH][T][HD] bf16   8 MB
    ushort* Ks    = (ushort*)(ws + 25165824);
    ushort* Vs    = (ushort*)(ws + 33554432);
    ushort* Ys    = (ushort*)(ws + 41943040);      // [B][T][C] bf16        8 MB
    ushort* VsT   = xb;                            // [B][NH][HD][T] bf16   8 MB

    cvtx<<<2048, 256, 0, stream>>>(x, xb, NB*NT*NC);
    tcvt<<<dim3(16,16), 256, 0, stream>>>(q_w, wqkvT, 1024, 1024);
    tcvt<<<dim3(16,32), 256, 0, stream>>>(kv_w, wqkvT + 1024*1024, 1024, 2048);
    tcvt<<<dim3(16,16), 256, 0, stream>>>(o_w, woT, 1024, 1024);
    gemm128<0><<<dim3(32,24), 256, 0, stream>>>(xb, wqkvT, q_b, kv_b, Qs, Ks, Vs, nullptr, 1024);
    vtr<<<dim3(32,32), 256, 0, stream>>>(Vs, VsT);
    attn_fwd<<<1024, 256, 0, stream>>>(Qs, Ks, VsT, Ys);
    gemm128<1><<<dim3(32,8), 256, 0, stream>>>(Ys, woT, o_b, nullptr, nullptr, nullptr, nullptr, out, 1024);
}

// Round 5
// 150.216 us; speedup vs baseline: 1.5778x; 1.0811x over previous
//
#include <hip/hip_runtime.h>
#include <hip/hip_bf16.h>

#define NB 2
#define NT 2048
#define NC 1024
#define NHD 16
#define HDD 64
#define LOG2E 1.4426950408889634f

typedef __attribute__((ext_vector_type(8))) short short8;
typedef __attribute__((ext_vector_type(4))) float f32x4;
typedef __attribute__((ext_vector_type(16))) float f32x16;

__device__ __forceinline__ ushort f2bf(float f) {
    union { float f; unsigned u; } v; v.f = f;
    unsigned u = v.u;
    unsigned r = (u + 0x7FFFu + ((u >> 16) & 1u)) >> 16;
    return (ushort)r;
}

__device__ __forceinline__ unsigned pkbf(float a, float b) {
    __hip_bfloat162 t = __float22bfloat162_rn(float2{a, b});
    unsigned u; __builtin_memcpy(&u, &t, 4); return u;
}

__device__ __forceinline__ void gload16(const ushort* g, ushort* l) {
    __builtin_amdgcn_global_load_lds((const __attribute__((address_space(1))) void*)g,
                                     (__attribute__((address_space(3))) void*)l, 16, 0, 0);
}

// ---------------- elementwise f32 -> bf16 ----------------
__global__ __launch_bounds__(256)
void cvtx(const float* __restrict__ src, ushort* __restrict__ dst, int n)
{
    int i = (blockIdx.x * 256 + threadIdx.x) * 8;
    if (i >= n) return;
    float4 a = *(const float4*)(src + i);
    float4 b = *(const float4*)(src + i + 4);
    short8 o;
    o[0] = (short)f2bf(a.x); o[1] = (short)f2bf(a.y);
    o[2] = (short)f2bf(a.z); o[3] = (short)f2bf(a.w);
    o[4] = (short)f2bf(b.x); o[5] = (short)f2bf(b.y);
    o[6] = (short)f2bf(b.z); o[7] = (short)f2bf(b.w);
    *(short8*)(dst + i) = o;
}

// ---------------- transpose + convert: W[K][N] f32 -> Wt[N][K] bf16 ----------------
__global__ __launch_bounds__(256)
void tcvt(const float* __restrict__ src, ushort* __restrict__ dst, int Kd, int Nd)
{
    __shared__ ushort tile[64][68];
    const int tid = threadIdx.x;
    const int kb = blockIdx.x * 64, nb = blockIdx.y * 64;
    const int r = tid >> 2, c = (tid & 3) * 16;
    const float* sp = src + (size_t)(kb + r) * Nd + nb + c;
#pragma unroll
    for (int i = 0; i < 16; i += 4) {
        float4 v = *(const float4*)(sp + i);
        tile[r][c + i + 0] = f2bf(v.x);
        tile[r][c + i + 1] = f2bf(v.y);
        tile[r][c + i + 2] = f2bf(v.z);
        tile[r][c + i + 3] = f2bf(v.w);
    }
    __syncthreads();
    ushort* dp = dst + (size_t)(nb + r) * Kd + kb + c;
#pragma unroll
    for (int i = 0; i < 16; i += 8) {
        short8 o;
#pragma unroll
        for (int j = 0; j < 8; j++) o[j] = (short)tile[c + i + j][r];
        *(short8*)(dp + i) = o;
    }
}

// ---------------- bf16 transpose: V[bh][t][d] -> Vt[bh][d][t] ----------------
__global__ __launch_bounds__(256)
void vtr(const ushort* __restrict__ src, ushort* __restrict__ dst)
{
    __shared__ ushort tile[64][66];
    const int tid = threadIdx.x;
    const int bh = blockIdx.y;
    const int t0 = blockIdx.x * 64;
    const int r = tid >> 2, c = (tid & 3) * 16;
    const ushort* sp = src + ((size_t)bh * NT + t0 + r) * HDD + c;
    *(short8*)&tile[r][c]     = *(const short8*)sp;
    *(short8*)&tile[r][c + 8] = *(const short8*)(sp + 8);
    __syncthreads();
    ushort* dp = dst + ((size_t)bh * HDD + r) * NT + t0 + c;
    short8 o0, o1;
#pragma unroll
    for (int j = 0; j < 8; j++) { o0[j] = (short)tile[c + j][r]; o1[j] = (short)tile[c + 8 + j][r]; }
    *(short8*)dp = o0;
    *(short8*)(dp + 8) = o1;
}

// ---------------- 128x128 bf16 MFMA GEMM (m97-style global_load_lds staging) ----------------
template<int MODE>
__global__ __launch_bounds__(256)
void gemm128(const ushort* __restrict__ A, const ushort* __restrict__ Bt,
             const float* __restrict__ bias0, const float* __restrict__ bias1,
             ushort* __restrict__ Qo, ushort* __restrict__ Ko, ushort* __restrict__ Vo,
             float* __restrict__ Fo, int Kdim)
{
    __shared__ ushort Al[128 * 32];
    __shared__ ushort Bl[128 * 32];
    const int tid = threadIdx.x;
    const int lane = tid & 63, w = tid >> 6;
    const int wr = (w >> 1) * 64, wc = (w & 1) * 64;
    const int lg = lane >> 4, lc = lane & 15;
    const int bm = blockIdx.x * 128, bn = blockIdx.y * 128;

    f32x4 acc[4][4] = {};

    const int srow = lane >> 2, scol = (lane & 3) * 8;

    for (int k0 = 0; k0 < Kdim; k0 += 32) {
        __syncthreads();
#pragma unroll
        for (int c = 0; c < 2; c++) {
            int seg = w * 2 + c;
            int row = seg * 16 + srow;
            gload16(A  + (size_t)(bm + row) * Kdim + k0 + scol, &Al[seg * 512]);
            gload16(Bt + (size_t)(bn + row) * Kdim + k0 + scol, &Bl[seg * 512]);
        }
        __syncthreads();
        short8 af[4], bfv[4];
#pragma unroll
        for (int mt = 0; mt < 4; mt++) af[mt] = *(const short8*)&Al[(wr + mt*16 + lc) * 32 + lg*8];
#pragma unroll
        for (int nt = 0; nt < 4; nt++) bfv[nt] = *(const short8*)&Bl[(wc + nt*16 + lc) * 32 + lg*8];
#pragma unroll
        for (int mt = 0; mt < 4; mt++)
#pragma unroll
            for (int nt = 0; nt < 4; nt++)
                acc[mt][nt] = __builtin_amdgcn_mfma_f32_16x16x32_bf16(af[mt], bfv[nt], acc[mt][nt], 0, 0, 0);
    }

#pragma unroll
    for (int mt = 0; mt < 4; mt++) {
#pragma unroll
        for (int nt = 0; nt < 4; nt++) {
#pragma unroll
            for (int rr = 0; rr < 4; rr++) {
                int m = bm + wr + mt*16 + lg*4 + rr;
                int n = bn + wc + nt*16 + lc;
                float v = acc[mt][nt][rr];
                if (MODE == 0) {
                    int b = m >> 11, t = m & 2047;
                    if (n < NC) {
                        float q = (v + bias0[n]) * (0.125f * LOG2E);
                        int hh = n >> 6, d = n & 63;
                        Qo[(((size_t)b*NHD + hh)*NT + t)*HDD + d] = f2bf(q);
                    } else {
                        int j = n - NC;
                        float val = v + bias1[j];
                        int s = j >> 10;
                        int jj = j & 1023;
                        int hh = jj >> 6, d = jj & 63;
                        ushort* dst = s ? Vo : Ko;
                        dst[(((size_t)b*NHD + hh)*NT + t)*HDD + d] = f2bf(val);
                    }
                } else {
                    Fo[(size_t)m * NC + n] = v + bias0[n];
                }
            }
        }
    }
}

// ---------------- flash attention, 32x32 swapped-operand form ----------------
// Block: 4 waves x 32 q-rows = 128 q rows. Grid 512 (16 q-chunks x 32 bh), heavy-first.
// QK^T = mfma(K,Q) -> S^T[kv][q], q = lane&31 (softmax lane-local).
// P -> bf16 via cvt_pk; cross-half exchange via shfl_xor(32) + select (unambiguous).
// PV = mfma(V^T, P) -> O^T[d][q], col q = lane -> per-lane rescale / 1/l.
__global__ __launch_bounds__(256, 3)
void attn_fwd(const ushort* __restrict__ Q, const ushort* __restrict__ K,
              const ushort* __restrict__ Vt, ushort* __restrict__ Y)
{
    __shared__ ushort sb[2 * 64 * 72];
    ushort* Kl = sb;              // [64 kv][72]  (K tile, d-minor)
    ushort* Vl = sb + 64 * 72;    // [64 d][72]   (V^T tile, kv-minor)

    const int tid = threadIdx.x;
    const int lane = tid & 63, w = tid >> 6;
    const int lo5 = lane & 31, hi = lane >> 5;
    const int qt = 15 - (int)(blockIdx.x >> 5);   // heavy chunks first
    const int bh = blockIdx.x & 31;
    const int b = bh >> 4, h = bh & 15;

    const ushort* Qp = Q + (size_t)bh * NT * HDD;
    const ushort* Kp = K + (size_t)bh * NT * HDD;
    const ushort* Vp = Vt + (size_t)bh * HDD * NT;

    const int bq0 = qt * 128;
    const int q0 = bq0 + w * 32;
    const int qlane = q0 + lo5;

    const float slope2 = (float)(h + 1) * (LOG2E / (float)NHD);

    // Q B-fragments: Q[qlane][kk*16 + 8*hi + j]
    short8 qf[4];
    {
        const ushort* qr = Qp + (size_t)qlane * HDD + 8 * hi;
#pragma unroll
        for (int kk = 0; kk < 4; kk++) qf[kk] = *(const short8*)(qr + kk * 16);
    }

    // per-register ALiBi bias (local space, tile offset sk folded into m shift)
    float bb[16];
#pragma unroll
    for (int r = 0; r < 16; r++) {
        int roff = (r & 3) + 8 * (r >> 2) + 4 * hi;
        bb[r] = slope2 * ((float)roff - (float)qlane);
    }

    float m_s = -1e30f, l_s = 0.f;
    f32x16 accO[2] = {};

    const int ntile = 2 * qt + 2;
    const int sr = tid >> 2, sd = (tid & 3) * 16;

    // prefetch tile 0
    short8 pk0, pk1, pv0, pv1;
    {
        const ushort* kp = Kp + (size_t)sr * HDD + sd;
        pk0 = *(const short8*)kp;
        pk1 = *(const short8*)(kp + 8);
        const ushort* vp = Vp + (size_t)sr * NT + sd;
        pv0 = *(const short8*)vp;
        pv1 = *(const short8*)(vp + 8);
    }

    for (int t = 0; t < ntile; t++) {
        const int kv0 = t * 64;
        __syncthreads();
        *(short8*)&Kl[sr * 72 + sd]     = pk0;
        *(short8*)&Kl[sr * 72 + sd + 8] = pk1;
        *(short8*)&Vl[sr * 72 + sd]     = pv0;
        *(short8*)&Vl[sr * 72 + sd + 8] = pv1;
        __syncthreads();

        if (t + 1 < ntile) {
            const int kv1 = kv0 + 64;
            const ushort* kp = Kp + (size_t)(kv1 + sr) * HDD + sd;
            pk0 = *(const short8*)kp;
            pk1 = *(const short8*)(kp + 8);
            const ushort* vp = Vp + (size_t)sr * NT + kv1 + sd;
            pv0 = *(const short8*)vp;
            pv1 = *(const short8*)(vp + 8);
        }

#pragma unroll
        for (int sub = 0; sub < 2; sub++) {
            const int kv0s = kv0 + sub * 32;
            if (kv0s > q0 + 31) continue;          // wave-uniform skip past diagonal

            // ---- QK^T: S^T[kv][q] ----
            f32x16 S = {};
#pragma unroll
            for (int kk = 0; kk < 4; kk++) {
                short8 kf = *(const short8*)&Kl[(sub * 32 + lo5) * 72 + kk * 16 + 8 * hi];
                S = __builtin_amdgcn_mfma_f32_32x32x16_bf16(kf, qf[kk], S, 0, 0, 0);
            }

            const float sk = slope2 * (float)kv0s;
            float mloc = m_s - sk;

            if (kv0s + 31 > q0) {                  // diagonal sub-block: mask
#pragma unroll
                for (int r = 0; r < 16; r++) {
                    int kvr = kv0s + (r & 3) + 8 * (r >> 2) + 4 * hi;
                    S[r] = (kvr > qlane) ? -1e30f : (S[r] + bb[r]);
                }
            } else {
#pragma unroll
                for (int r = 0; r < 16; r++) S[r] = S[r] + bb[r];
            }

            float rmax = S[0];
#pragma unroll
            for (int r = 1; r < 16; r++) rmax = fmaxf(rmax, S[r]);
            rmax = fmaxf(rmax, __shfl_xor(rmax, 32));

            if (__any(rmax - mloc > 8.0f)) {       // defer-max (T13)
                float mn = fmaxf(mloc, rmax);
                float sc = __builtin_amdgcn_exp2f(mloc - mn);
                mloc = mn;
                l_s *= sc;
#pragma unroll
                for (int dt = 0; dt < 2; dt++)
#pragma unroll
                    for (int r = 0; r < 16; r++) accO[dt][r] *= sc;
            }
            m_s = mloc + sk;

            float p[16], sum = 0.f;
#pragma unroll
            for (int r = 0; r < 16; r++) {
                p[r] = __builtin_amdgcn_exp2f(S[r] - mloc);
                sum += p[r];
            }
            sum += __shfl_xor(sum, 32);
            l_s += sum;

            // ---- P -> bf16 PV B-fragments; cross-half exchange via shfl_xor(32) ----
            // p[r] = P[kv_local = (r&3)+8*(r>>2)+4*hi][q=lo5]
            // target frag word wN of half hi must hold P[kv = 16*frag + 8*hi + 2N..2N+1]
            unsigned pw[8], px[8];
#pragma unroll
            for (int i = 0; i < 8; i++) pw[i] = pkbf(p[2 * i], p[2 * i + 1]);
#pragma unroll
            for (int i = 0; i < 8; i++) px[i] = __shfl_xor(pw[i], 32);
            union { unsigned u[4]; short8 s; } fa0, fa1;
            fa0.u[0] = hi ? px[2] : pw[0];
            fa0.u[1] = hi ? px[3] : pw[1];
            fa0.u[2] = hi ? pw[2] : px[0];
            fa0.u[3] = hi ? pw[3] : px[1];
            fa1.u[0] = hi ? px[6] : pw[4];
            fa1.u[1] = hi ? px[7] : pw[5];
            fa1.u[2] = hi ? pw[6] : px[4];
            fa1.u[3] = hi ? pw[7] : px[5];

            // ---- PV: O^T[d][q] += V^T x P ----
#pragma unroll
            for (int dt = 0; dt < 2; dt++) {
                short8 vf0 = *(const short8*)&Vl[(dt * 32 + lo5) * 72 + sub * 32 + 8 * hi];
                short8 vf1 = *(const short8*)&Vl[(dt * 32 + lo5) * 72 + sub * 32 + 16 + 8 * hi];
                accO[dt] = __builtin_amdgcn_mfma_f32_32x32x16_bf16(vf0, fa0.s, accO[dt], 0, 0, 0);
                accO[dt] = __builtin_amdgcn_mfma_f32_32x32x16_bf16(vf1, fa1.s, accO[dt], 0, 0, 0);
            }
        }
    }

    // ---- epilogue: per-lane 1/l, transpose via LDS, coalesced store ----
    const float invl = __builtin_amdgcn_rcpf(l_s);
    __syncthreads();                               // all waves done with Kl/Vl
    ushort* myO = sb + w * 32 * 72;                // [32 q][72] per wave
#pragma unroll
    for (int dt = 0; dt < 2; dt++)
#pragma unroll
        for (int r = 0; r < 16; r++) {
            int d = dt * 32 + (r & 3) + 8 * (r >> 2) + 4 * hi;
            myO[lo5 * 72 + d] = f2bf(accO[dt][r] * invl);
        }
    __syncthreads();
    const int orow = lane >> 1, ocol = (lane & 1) * 32;
    const int qg = q0 + orow;
    ushort* yp = Y + ((size_t)b * NT + qg) * NC + h * HDD + ocol;
#pragma unroll
    for (int c = 0; c < 4; c++)
        *(short8*)(yp + c * 8) = *(const short8*)&myO[orow * 72 + ocol + c * 8];
}

extern "C" void kernel_launch(void* const* d_in, const int* in_sizes, int n_in,
                              void* d_out, int out_size, void* d_ws, size_t ws_size,
                              hipStream_t stream)
{
    const float* x    = (const float*)d_in[0];
    const float* q_w  = (const float*)d_in[1];
    const float* q_b  = (const float*)d_in[2];
    const float* kv_w = (const float*)d_in[3];
    const float* kv_b = (const float*)d_in[4];
    const float* o_w  = (const float*)d_in[5];
    const float* o_b  = (const float*)d_in[6];
    float* out = (float*)d_out;

    char* ws = (char*)d_ws;
    ushort* xb    = (ushort*)(ws);                 // [4096][1024] bf16  8 MB (reused as VsT)
    ushort* wqkvT = (ushort*)(ws + 8388608);       // [3072][1024] bf16  6 MB
    ushort* woT   = (ushort*)(ws + 14680064);      // [1024][1024] bf16  2 MB
    ushort* Qs    = (ushort*)(ws + 16777216);      // [B][NH][T][HD]
    ushort* Ks    = (ushort*)(ws + 25165824);
    ushort* Vs    = (ushort*)(ws + 33554432);
    ushort* Ys    = (ushort*)(ws + 41943040);      // [B][T][C]
    ushort* VsT   = xb;                            // [B][NH][HD][T]

    cvtx<<<2048, 256, 0, stream>>>(x, xb, NB*NT*NC);
    tcvt<<<dim3(16,16), 256, 0, stream>>>(q_w, wqkvT, 1024, 1024);
    tcvt<<<dim3(16,32), 256, 0, stream>>>(kv_w, wqkvT + 1024*1024, 1024, 2048);
    tcvt<<<dim3(16,16), 256, 0, stream>>>(o_w, woT, 1024, 1024);
    gemm128<0><<<dim3(32,24), 256, 0, stream>>>(xb, wqkvT, q_b, kv_b, Qs, Ks, Vs, nullptr, 1024);
    vtr<<<dim3(32,32), 256, 0, stream>>>(Vs, VsT);
    attn_fwd<<<512, 256, 0, stream>>>(Qs, Ks, VsT, Ys);
    gemm128<1><<<dim3(32,8), 256, 0, stream>>>(Ys, woT, o_b, nullptr, nullptr, nullptr, nullptr, out, 1024);
}